// Round 3
// baseline (303.307 us; speedup 1.0000x reference)
//
#include <hip/hip_runtime.h>
#include <math.h>

// All inputs/outputs fp32 (verified R2).
// R10: k_sample per-point dedupe of 512 tap rows. 277.2us measured.
// R11: split k_edge: k_attn (grid 128, attention+oproj+norm2+pe -> nqin) and two
// output-tiled k_lin GEMMs (nq, off|attw) with fp32 weights read once-ish.
// Removes 196MB of per-block weight streaming + ~10K barriers; attention no
// longer computed redundantly 3x. k_sample: per-level dedupe scan (4x shorter).

typedef unsigned int uint;

__device__ __forceinline__ float lo16(uint u) { return __uint_as_float(u << 16); }
__device__ __forceinline__ float hi16(uint u) { return __uint_as_float(u & 0xFFFF0000u); }
__device__ __forceinline__ uint bfr(float x) {  // fp32 -> bf16 bits, RNE
    uint u = __float_as_uint(x);
    return (u + 0x7FFFu + ((u >> 16) & 1u)) >> 16;
}

__device__ __forceinline__ float block_sum256w(float v, float* red) {
    int t = threadIdx.x;
    if (t < 256) red[t] = v;
    __syncthreads();
    for (int st = 128; st > 0; st >>= 1) {
        if (t < st) red[t] += red[t + st];
        __syncthreads();
    }
    float r = red[0]; __syncthreads();
    return r;
}

// ---- tiled GEMM unit (R4-verified): 64 rows x 8 outputs ----
template <int K, int MI, int MO>
__device__ void gemm_unit(const float* __restrict__ IN, const float* __restrict__ IN2,
                          const float* __restrict__ W, const float* __restrict__ B,
                          float* __restrict__ OUT, int O, int OG, int u, float* smem) {
    constexpr int KC = 128;
    constexpr int LDT = KC + 4;
    float* tile = smem;
    int og = u % OG, rg = u / OG;
    int o0 = og * 8, r0 = rg * 64;
    int t = threadIdx.x;
    int r = t & 63;
    int ol = __builtin_amdgcn_readfirstlane(t >> 6);
    int oa = o0 + ol, ob = o0 + 4 + ol;
    const float* Wa = W + (size_t)oa * K;
    const float* Wb = W + (size_t)ob * K;
    float Ba = B[oa], Bb = B[ob];
    float acca = 0.f, accb = 0.f;
    for (int c = 0; c < K / KC; c++) {
        for (int idx = t; idx < 64 * KC; idx += 256) {
            int rr = idx >> 7, ii = idx & (KC - 1);
            int row = r0 + rr, col = c * KC + ii;
            float v;
            if (MI == 0) {
                v = IN[(size_t)row * K + col];
            } else {
                float tv = IN[row * 256 + col];
                v = (o0 < 512) ? tv + IN2[row * 256 + col] : tv;
            }
            tile[rr * LDT + ii] = v;
        }
        __syncthreads();
        const float4* wa4 = (const float4*)(Wa + c * KC);
        const float4* wb4 = (const float4*)(Wb + c * KC);
        const float4* trow = (const float4*)(tile + r * LDT);
        #pragma unroll
        for (int i4 = 0; i4 < KC / 4; i4++) {
            float4 x4 = trow[i4];
            float4 a4 = wa4[i4];
            float4 b4 = wb4[i4];
            acca += x4.x * a4.x; acca += x4.y * a4.y;
            acca += x4.z * a4.z; acca += x4.w * a4.w;
            accb += x4.x * b4.x; accb += x4.y * b4.y;
            accb += x4.z * b4.z; accb += x4.w * b4.w;
        }
        __syncthreads();
    }
    acca += Ba; accb += Bb;
    if (MO == 2) {
        if (oa < 256) acca *= 0.17677669529663687f;
        if (ob < 256) accb *= 0.17677669529663687f;
    }
    OUT[(size_t)(r0 + r) * O + oa] = acca;
    OUT[(size_t)(r0 + r) * O + ob] = accb;
}

// ---- fp32 transpose unit: out[c*256 + r] = in[r][c] (R,C mult of 32) ----
__device__ void transpose_unit(const float* __restrict__ in, float* __restrict__ out,
                               int R, int C, int u, float* smem) {
    int TC = C >> 5;
    int tc = u % TC, tr = u / TC;
    int t = threadIdx.x;
    int lr = t >> 5, lc = t & 31;
    #pragma unroll
    for (int rr = 0; rr < 32; rr += 8)
        smem[(rr + lr) * 33 + lc] = in[(size_t)(tr * 32 + rr + lr) * C + tc * 32 + lc];
    __syncthreads();
    #pragma unroll
    for (int rr = 0; rr < 32; rr += 8)
        out[(size_t)(tc * 32 + rr + lr) * R + tr * 32 + lc] = smem[lc * 33 + rr + lr];
    __syncthreads();
}

// ---- transpose+bf16-pack: P[(k2)*S + F + r] = pack(in[r][2k2], in[r][2k2+1]) ----
__device__ void tpack_unit(const float* __restrict__ in, uint* __restrict__ P,
                           int C, int S, int F, int u, float* smem) {
    int TC = C >> 5;
    int tc = u % TC, tr = u / TC;
    int t = threadIdx.x;
    int lr = t >> 5, lc = t & 31;
    #pragma unroll
    for (int rr = 0; rr < 32; rr += 8)
        smem[(rr + lr) * 33 + lc] = in[(size_t)(tr * 32 + rr + lr) * C + tc * 32 + lc];
    __syncthreads();
    #pragma unroll
    for (int rep = 0; rep < 2; rep++) {
        int idx = rep * 256 + t;
        int c2 = idx >> 5, r = idx & 31;
        uint w0 = bfr(smem[r * 33 + 2 * c2]);
        uint w1 = bfr(smem[r * 33 + 2 * c2 + 1]);
        P[(size_t)(tc * 16 + c2) * S + F + tr * 32 + r] = (w1 << 16) | w0;
    }
    __syncthreads();
}

// ---------------- S1: qkv gemm + weight transposes/packs ----------------
// grid 896, block 256
__global__ __launch_bounds__(256) void k_prep(const float* __restrict__ tgt,
                                              const float* __restrict__ qpos,
                                              const float* __restrict__ ipw,
                                              const float* __restrict__ ipb,
                                              const float* __restrict__ opw,
                                              const float* __restrict__ ojw,
                                              const float* __restrict__ valw,
                                              const float* __restrict__ l1w,
                                              const float* __restrict__ l2w,
                                              float* __restrict__ qkv,
                                              float* __restrict__ opwT,
                                              float* __restrict__ ojwT,
                                              float* __restrict__ valwT,
                                              uint* __restrict__ Pl1,
                                              uint* __restrict__ Pl2) {
    __shared__ __align__(16) float smem[8448];
    int u = blockIdx.x;
    if (u < 192)       gemm_unit<256, 1, 2>(tgt, qpos, ipw, ipb, qkv, 768, 96, u, smem);
    else if (u < 256)  transpose_unit(opw, opwT, 256, 256, u - 192, smem);
    else if (u < 320)  transpose_unit(ojw, ojwT, 256, 256, u - 256, smem);
    else if (u < 384)  transpose_unit(valw, valwT, 256, 256, u - 320, smem);
    else if (u < 640)  tpack_unit(l1w, Pl1, 256, 1024, 0, u - 384, smem);
    else               tpack_unit(l2w, Pl2, 1024, 256, 0, u - 640, smem);
}

// ---- geometry for edge e, point j ----
__device__ __forceinline__ void edge_geom(const float* __restrict__ ec, int e, int j,
                                          float* pxs, float* pys,
                                          float& fminx, float& fminy,
                                          float& cxf, float& cyf) {
    float ax = ec[e * 4 + 0], ay = ec[e * 4 + 1];
    float bx = ec[e * 4 + 2], by = ec[e * 4 + 3];
    float dx = bx - ax, dy = by - ay;
    float tj = 0.5f * (float)j;
    float ptx = __fadd_rn(ax, __fmul_rn(tj, dx));
    float pty = __fadd_rn(ay, __fmul_rn(tj, dy));
    cxf = floorf(ptx); cyf = floorf(pty);
    int minx = max((int)cxf - 128, 0); if (minx + 256 > 2048) minx = 2048 - 256;
    int miny = max((int)cyf - 128, 0); if (miny + 256 > 2048) miny = 2048 - 256;
    fminx = (float)minx; fminy = (float)miny;
    float tlx, thx, tly, thy;
    if (dx == 0.f) { tlx = 0.f; thx = 1.f; }
    else { float u1 = (fminx - ax) / dx, u2 = (fminx + 256.f - ax) / dx; tlx = fminf(u1, u2); thx = fmaxf(u1, u2); }
    if (dy == 0.f) { tly = 0.f; thy = 1.f; }
    else { float u1 = (fminy - ay) / dy, u2 = (fminy + 256.f - ay) / dy; tly = fminf(u1, u2); thy = fmaxf(u1, u2); }
    float t0 = fmaxf(fmaxf(tlx, tly), 0.f);
    float t1 = fmaxf(fminf(fminf(thx, thy), 1.f), t0);
    pxs[0] = __fadd_rn(ax, __fmul_rn(t0, dx)); pys[0] = __fadd_rn(ay, __fmul_rn(t0, dy));
    pxs[1] = __fadd_rn(ax, __fmul_rn(t1, dx)); pys[1] = __fadd_rn(ay, __fmul_rn(t1, dy));
    pxs[2] = cxf; pys[2] = cyf;
}

// ---------------- S2a: per-EDGE attention + oproj + norm2 + pe -> nqin ----------------
// grid 128, block 1024
__global__ __launch_bounds__(1024) void k_attn(const float* __restrict__ qkv,
                                               const float* __restrict__ tgt,
                                               const float* __restrict__ qpos,
                                               const float* __restrict__ opwT,
                                               const float* __restrict__ opb,
                                               const float* __restrict__ n2w,
                                               const float* __restrict__ n2b,
                                               const float* __restrict__ ec,
                                               float* __restrict__ x1,
                                               float* __restrict__ nqin,
                                               float* __restrict__ refxy,
                                               int* __restrict__ lxly) {
    int e = blockIdx.x, t = threadIdx.x;
    __shared__ __align__(16) float SH[2832];
    float* sq   = SH;            // 256
    float* sS   = SH + 256;      // 1024
    float* smax = SH + 1280;     // 8
    float* ssum = SH + 1288;     // 8
    float* srow = SH + 1296;     // 256
    float* part = SH + 1552;     // 1024
    float* red  = SH + 2576;     // 256
    // ---- attention ----
    if (t < 256) sq[t] = qkv[e * 768 + t];
    __syncthreads();
    {
        int h = t >> 7, f = t & 127;
        const float* kf = qkv + f * 768 + 256 + h * 32;
        const float* qh = sq + h * 32;
        float s = 0.f;
        #pragma unroll 8
        for (int d = 0; d < 32; d++) s += qh[d] * kf[d];
        sS[t] = s;
    }
    __syncthreads();
    if (t < 8) {
        float m = -1e30f;
        for (int f = 0; f < 128; f++) m = fmaxf(m, sS[t * 128 + f]);
        smax[t] = m;
    }
    __syncthreads();
    sS[t] = __expf(sS[t] - smax[t >> 7]);
    __syncthreads();
    if (t < 8) {
        float s = 0.f;
        for (int f = 0; f < 128; f++) s += sS[t * 128 + f];
        ssum[t] = 1.f / s;
    }
    __syncthreads();
    {
        int o = t & 255, c = t >> 8, h = o >> 5, d = o & 31;
        float acc = 0.f;
        #pragma unroll 8
        for (int f = c * 32; f < c * 32 + 32; f++)
            acc += sS[h * 128 + f] * qkv[f * 768 + 512 + h * 32 + d];
        part[t] = acc;
    }
    __syncthreads();
    if (t < 256) srow[t] = (part[t] + part[256 + t] + part[512 + t] + part[768 + t]) * ssum[t >> 5];
    __syncthreads();
    // ---- oproj ----
    {
        int o = t & 255, c = t >> 8;
        float acc = 0.f;
        #pragma unroll 8
        for (int i = c * 64; i < c * 64 + 64; i++) acc += srow[i] * opwT[(size_t)i * 256 + o];
        part[t] = acc;
    }
    __syncthreads();
    // ---- norm2 -> x1, xq (replicated into nqin rows 3e..3e+2, cols 0-255) ----
    {
        float acc = 0.f;
        if (t < 256) acc = part[t] + part[256 + t] + part[512 + t] + part[768 + t] + opb[t] + tgt[e * 256 + t];
        float mean = block_sum256w(acc, red) * (1.f / 256.f);
        float d0 = acc - mean;
        float var = block_sum256w((t < 256) ? d0 * d0 : 0.f, red) * (1.f / 256.f);
        if (t < 256) {
            float xln = d0 * rsqrtf(var + 1e-5f) * n2w[t] + n2b[t];
            x1[e * 256 + t] = xln;
            float xqv = xln + qpos[e * 256 + t];
            nqin[(size_t)(3 * e + 0) * 640 + t] = xqv;
            nqin[(size_t)(3 * e + 1) * 640 + t] = xqv;
            nqin[(size_t)(3 * e + 2) * 640 + t] = xqv;
        }
    }
    // ---- pos-encode for 3 points (3x384) -> nqin cols 256-639 ----
    for (int idx = t; idx < 1152; idx += 1024) {
        int j = idx / 384, w = idx - j * 384;
        float pxs[3], pys[3], fmx, fmy, cxf, cyf;
        edge_geom(ec, e, j, pxs, pys, fmx, fmy, cxf, cyf);
        int jj = w >> 7, tt = w & 127, i = tt & 63, kk = i >> 1;
        float invd = __expf(-(float)kk * (9.210340371976184f / 32.f));  // 10000^(-kk/32)
        float vv = (tt < 64) ? pys[jj] : pxs[jj];
        float pp = vv * invd;
        nqin[(size_t)(3 * e + j) * 640 + 256 + w] = (i & 1) ? __cosf(pp) : __sinf(pp);
    }
    if (t < 3) {
        int n = 3 * e + t;
        float pxs[3], pys[3], fmx, fmy, cxf, cyf;
        edge_geom(ec, e, t, pxs, pys, fmx, fmy, cxf, cyf);
        refxy[n * 2 + 0] = (cxf - fmx) * (1.f / 256.f);
        refxy[n * 2 + 1] = (cyf - fmy) * (1.f / 256.f);
        lxly[n * 8 + 0] = (int)rintf(fmx * 0.125f);
        lxly[n * 8 + 1] = (int)rintf(fmx * 0.0625f);
        lxly[n * 8 + 2] = (int)rintf(fmx * 0.03125f);
        lxly[n * 8 + 3] = (int)rintf(fmx * 0.015625f);
        lxly[n * 8 + 4] = (int)rintf(fmy * 0.125f);
        lxly[n * 8 + 5] = (int)rintf(fmy * 0.0625f);
        lxly[n * 8 + 6] = (int)rintf(fmy * 0.03125f);
        lxly[n * 8 + 7] = (int)rintf(fmy * 0.015625f);
    }
}

// ---------------- S2b/S2c: generic tiled linear, 64 rows x 8 outs per block ----------------
// W1 covers outputs [0,256); W2 covers [256, ...). OUT[row*out_stride + o] = IN@W^T + B.
template <int K>
__global__ __launch_bounds__(256) void k_lin(const float* __restrict__ IN,
                                             const float* __restrict__ W1,
                                             const float* __restrict__ B1,
                                             const float* __restrict__ W2,
                                             const float* __restrict__ B2,
                                             float* __restrict__ OUT,
                                             int out_stride, int OG) {
    constexpr int KC = 128;
    constexpr int LDT = KC + 4;
    __shared__ __align__(16) float tile[64 * LDT];
    int u = blockIdx.x;
    int og = u % OG, rg = u / OG;
    int o0 = og * 8, r0 = rg * 64;
    int t = threadIdx.x;
    int r = t & 63;
    int ol = __builtin_amdgcn_readfirstlane(t >> 6);
    int oa = o0 + ol, ob = o0 + 4 + ol;
    const float* Wa = (oa < 256) ? W1 + (size_t)oa * K : W2 + (size_t)(oa - 256) * K;
    const float* Wb = (ob < 256) ? W1 + (size_t)ob * K : W2 + (size_t)(ob - 256) * K;
    float Ba = (oa < 256) ? B1[oa] : B2[oa - 256];
    float Bb = (ob < 256) ? B1[ob] : B2[ob - 256];
    float acca = 0.f, accb = 0.f;
    for (int c = 0; c < K / KC; c++) {
        for (int idx = t; idx < 64 * KC; idx += 256) {
            int rr = idx >> 7, ii = idx & (KC - 1);
            tile[rr * LDT + ii] = IN[(size_t)(r0 + rr) * K + c * KC + ii];
        }
        __syncthreads();
        const float4* wa4 = (const float4*)(Wa + c * KC);
        const float4* wb4 = (const float4*)(Wb + c * KC);
        const float4* trow = (const float4*)(tile + r * LDT);
        #pragma unroll
        for (int i4 = 0; i4 < KC / 4; i4++) {
            float4 x4 = trow[i4];
            float4 a4 = wa4[i4];
            float4 b4 = wb4[i4];
            acca += x4.x * a4.x; acca += x4.y * a4.y;
            acca += x4.z * a4.z; acca += x4.w * a4.w;
            accb += x4.x * b4.x; accb += x4.y * b4.y;
            accb += x4.z * b4.z; accb += x4.w * b4.w;
        }
        __syncthreads();
    }
    OUT[(size_t)(r0 + r) * out_stride + oa] = acca + Ba;
    OUT[(size_t)(r0 + r) * out_stride + ob] = accb + Bb;
}

// ---------------- S3: deformable sampling, per-point with tap dedupe ----------------
// grid N=384, block 1024. Taps re-indexed level-major: rows from different levels
// live in disjoint index ranges, so the first-occurrence scan stays within the
// 128-tap level segment.
__global__ __launch_bounds__(1024) void k_sample(const float* __restrict__ offatr,
                                                 const float* __restrict__ refxy,
                                                 const float* __restrict__ vr,
                                                 const int* __restrict__ lxly,
                                                 const float* __restrict__ src,
                                                 const unsigned char* __restrict__ mask,
                                                 const float* __restrict__ valwT,
                                                 const float* __restrict__ valb,
                                                 float* __restrict__ ca) {
    int n = blockIdx.x, t = threadIdx.x;
    __shared__ float sl[128];          // logits [h][16]
    __shared__ float sm[8], sinv[8];
    __shared__ float sw[512];          // tap weights
    __shared__ int   sg[512];          // tap global rows (-1 invalid)
    __shared__ int   lead[512];
    __shared__ int   rk[512];          // leader -> compact rank
    __shared__ int   ulist[512];       // rank -> global row
    __shared__ int   redi[256];
    __shared__ float uw[512 * 8];      // per-unique per-head weight (16 KB)
    __shared__ float agg[8 * 256];     // aggregated value rows per head (8 KB)
    __shared__ float pcs[64];
    __shared__ float pagg[1024];

    if (t < 128) sl[t] = offatr[(size_t)n * 384 + 256 + t];
    #pragma unroll
    for (int z = 0; z < 4; z++) uw[z * 1024 + t] = 0.f;
    __syncthreads();
    if (t < 8) {
        float m = -1e30f;
        for (int i = 0; i < 16; i++) m = fmaxf(m, sl[t * 16 + i]);
        float s = 0.f;
        for (int i = 0; i < 16; i++) s += __expf(sl[t * 16 + i] - m);
        sm[t] = m; sinv[t] = 1.f / s;
    }
    __syncthreads();
    // ---- compute all 512 taps (level-major: t = l*128 + h*16 + pp*4 + tap) ----
    if (t < 512) {
        int l = t >> 7, rem = t & 127;
        int h = rem >> 4, pp = (rem >> 2) & 3, tap = t & 3;
        int s = 32 >> l, wl = 256 >> l;
        const int img_starts[4] = {0, 65536, 81920, 86016};
        float a = __expf(sl[h * 16 + l * 4 + pp] - sm[h]) * sinv[h];
        float slv = (float)s;
        float gx = refxy[n * 2 + 0] * vr[l * 2 + 0] + offatr[(size_t)n * 384 + h * 32 + l * 8 + pp * 2 + 0] / slv;
        float gy = refxy[n * 2 + 1] * vr[l * 2 + 1] + offatr[(size_t)n * 384 + h * 32 + l * 8 + pp * 2 + 1] / slv;
        float px = gx * slv - 0.5f, py = gy * slv - 0.5f;
        float x0 = floorf(px), y0 = floorf(py);
        float fx = px - x0, fy = py - y0;
        int xi = (int)x0 + (tap & 1), yi = (int)y0 + (tap >> 1);
        float wtt = ((tap & 1) ? fx : (1.f - fx)) * ((tap >> 1) ? fy : (1.f - fy));
        int g = -1;
        if (xi >= 0 && xi < s && yi >= 0 && yi < s) {
            int col = lxly[n * 8 + l] + xi;
            int row = lxly[n * 8 + 4 + l] + yi;
            g = img_starts[l] + row * wl + col;
            if (mask[g]) g = -1;  // masked rows zeroed (incl. bias)
        }
        sw[t] = a * wtt;
        sg[t] = g;
    }
    __syncthreads();
    // ---- first-occurrence dedupe (within level segment only) ----
    int fi = -1;
    if (t < 512) {
        int g = sg[t];
        if (g >= 0) {
            fi = t;
            int base = t & ~127;  // level segment start
            for (int jj = base; jj < t; jj++) if (sg[jj] == g) { fi = jj; break; }
        }
        lead[t] = (fi == t) ? 1 : 0;
    }
    __syncthreads();
    // leader ranks (deterministic compaction) + parallel count of leaders
    if (t < 512 && fi == t) {
        int r = 0;
        for (int jj = 0; jj < t; jj++) r += lead[jj];
        rk[t] = r;
        ulist[r] = sg[t];
    }
    if (t < 256) redi[t] = lead[t] + lead[t + 256];
    __syncthreads();
    for (int st = 128; st > 0; st >>= 1) {
        if (t < st) redi[t] += redi[t + st];
        __syncthreads();
    }
    // ---- accumulate per-unique per-head weights ----
    if (t < 512 && fi >= 0) {
        int h = (t >> 4) & 7;
        atomicAdd(&uw[rk[fi] * 8 + h], sw[t]);
    }
    __syncthreads();
    int U = redi[0];
    // ---- main gather: each unique row read once, applied to 2 heads/thread ----
    {
        int ch = t & 255, q = t >> 8;
        float a0 = 0.f, a1 = 0.f;
        for (int u = 0; u < U; u++) {
            int g = ulist[u];
            float v = src[(size_t)g * 256 + ch];
            a0 += uw[u * 8 + 2 * q] * v;
            a1 += uw[u * 8 + 2 * q + 1] * v;
        }
        agg[(2 * q) * 256 + ch] = a0;
        agg[(2 * q + 1) * 256 + ch] = a1;
    }
    // csum partials (deterministic)
    if (t < 64) {
        int h = t >> 3, p = t & 7;
        float s = 0.f;
        for (int u = p; u < U; u += 8) s += uw[u * 8 + h];
        pcs[t] = s;
    }
    __syncthreads();
    // ---- fused value projection: out[h][32] ----
    {
        int h = t >> 7, rem = t & 127, o = rem & 31, kc = rem >> 5;
        const float* ag = agg + h * 256 + kc * 64;
        const float* w = valwT + (size_t)(kc * 64) * 256 + h * 32 + o;
        float pv = 0.f;
        #pragma unroll 8
        for (int i = 0; i < 64; i++) pv += ag[i] * w[(size_t)i * 256];
        pagg[t] = pv;
    }
    __syncthreads();
    if (t < 256) {
        int h = t >> 5, o = t & 31;
        float cs = pcs[h * 8 + 0] + pcs[h * 8 + 1] + pcs[h * 8 + 2] + pcs[h * 8 + 3]
                 + pcs[h * 8 + 4] + pcs[h * 8 + 5] + pcs[h * 8 + 6] + pcs[h * 8 + 7];
        float r = pagg[h * 128 + o] + pagg[h * 128 + 32 + o] + pagg[h * 128 + 64 + o] + pagg[h * 128 + 96 + o];
        ca[(size_t)n * 256 + h * 32 + o] = r + cs * valb[h * 32 + o];
    }
}

// ---------------- S4: pool + oproj + norm1 + ffn1 + ffn2 + norm3 ----------------
// grid 128 (per edge), block 1024; ffn weights bf16-packed
__global__ __launch_bounds__(1024) void k_tail(const float* __restrict__ ca,
                                               const float* __restrict__ x1,
                                               const float* __restrict__ ojwT,
                                               const float* __restrict__ ojb,
                                               const float* __restrict__ n1w,
                                               const float* __restrict__ n1b,
                                               const uint* __restrict__ Pl1,
                                               const float* __restrict__ l1b,
                                               const uint* __restrict__ Pl2,
                                               const float* __restrict__ l2b,
                                               const float* __restrict__ n3w,
                                               const float* __restrict__ n3b,
                                               float* __restrict__ out) {
    int e = blockIdx.x, t = threadIdx.x;
    __shared__ float row[256], red[256], x2s[256], h1s[1024], part[1024];
    if (t < 256)
        row[t] = (ca[(3 * e) * 256 + t] + ca[(3 * e + 1) * 256 + t] + ca[(3 * e + 2) * 256 + t]) * (1.f / 3.f);
    __syncthreads();
    // oproj: 256 outputs x 4 chunks of 64
    {
        int o = t & 255, c = t >> 8;
        float acc = 0.f;
        #pragma unroll 8
        for (int i = c * 64; i < c * 64 + 64; i++) acc += row[i] * ojwT[(size_t)i * 256 + o];
        part[t] = acc;
    }
    __syncthreads();
    // norm1
    {
        float acc = 0.f;
        if (t < 256) acc = part[t] + part[256 + t] + part[512 + t] + part[768 + t] + ojb[t] + x1[e * 256 + t];
        float mean = block_sum256w(acc, red) * (1.f / 256.f);
        float d0 = acc - mean;
        float var = block_sum256w((t < 256) ? d0 * d0 : 0.f, red) * (1.f / 256.f);
        if (t < 256) x2s[t] = d0 * rsqrtf(var + 1e-5f) * n1w[t] + n1b[t];
    }
    __syncthreads();
    // ffn1: one output per thread, packed K=256 (128 uints)
    {
        float acc = l1b[t];
        #pragma unroll 8
        for (int k2 = 0; k2 < 128; k2++) {
            uint u = Pl1[(size_t)k2 * 1024 + t];
            acc += x2s[2 * k2] * lo16(u);
            acc += x2s[2 * k2 + 1] * hi16(u);
        }
        h1s[t] = fmaxf(acc, 0.f);
    }
    __syncthreads();
    // ffn2: 256 outputs x 4 chunks of 128 packed
    {
        int o = t & 255, c = t >> 8;
        float acc = 0.f;
        #pragma unroll 8
        for (int k2 = c * 128; k2 < c * 128 + 128; k2++) {
            uint u = Pl2[(size_t)k2 * 256 + o];
            acc += h1s[2 * k2] * lo16(u);
            acc += h1s[2 * k2 + 1] * hi16(u);
        }
        part[t] = acc;
    }
    __syncthreads();
    // norm3 -> out
    {
        float acc = 0.f;
        if (t < 256) acc = part[t] + part[256 + t] + part[512 + t] + part[768 + t] + l2b[t] + x2s[t];
        float mean = block_sum256w(acc, red) * (1.f / 256.f);
        float d0 = acc - mean;
        float var = block_sum256w((t < 256) ? d0 * d0 : 0.f, red) * (1.f / 256.f);
        if (t < 256) out[e * 256 + t] = d0 * rsqrtf(var + 1e-5f) * n3w[t] + n3b[t];
    }
}

extern "C" void kernel_launch(void* const* d_in, const int* in_sizes, int n_in,
                              void* d_out, int out_size, void* d_ws, size_t ws_size,
                              hipStream_t stream) {
    (void)in_sizes; (void)n_in; (void)out_size; (void)ws_size;
    const float* tgt  = (const float*)d_in[0];
    const float* qpos = (const float*)d_in[1];
    const float* ec   = (const float*)d_in[2];
    const float* src  = (const float*)d_in[3];
    const unsigned char* mask = (const unsigned char*)d_in[4];
    const float* vr   = (const float*)d_in[5];
    const float* ipw  = (const float*)d_in[6];
    const float* ipb  = (const float*)d_in[7];
    const float* opw  = (const float*)d_in[8];
    const float* opb  = (const float*)d_in[9];
    const float* n1w  = (const float*)d_in[10];
    const float* n1b  = (const float*)d_in[11];
    const float* n2w  = (const float*)d_in[12];
    const float* n2b  = (const float*)d_in[13];
    const float* n3w  = (const float*)d_in[14];
    const float* n3b  = (const float*)d_in[15];
    const float* l0w  = (const float*)d_in[16];
    const float* l0b  = (const float*)d_in[17];
    const float* l1w  = (const float*)d_in[18];
    const float* l1b  = (const float*)d_in[19];
    const float* l2w  = (const float*)d_in[20];
    const float* l2b  = (const float*)d_in[21];
    const float* offw = (const float*)d_in[22];
    const float* offb = (const float*)d_in[23];
    const float* aww  = (const float*)d_in[24];
    const float* awb  = (const float*)d_in[25];
    const float* valw = (const float*)d_in[26];
    const float* valb = (const float*)d_in[27];
    const float* ojw  = (const float*)d_in[28];
    const float* ojb  = (const float*)d_in[29];

    float* ws     = (float*)d_ws;
    float* qkv    = ws;                    // 98304
    float* x1     = ws + 98304;            // 32768
    float* offatr = ws + 131072;           // 147456
    float* ca     = ws + 278528;           // 98304
    float* refxy  = ws + 376832;           // 768
    int*   lxly   = (int*)(ws + 377600);   // 3072
    float* opwT   = ws + 380672;           // 65536
    float* ojwT   = ws + 446208;           // 65536
    float* valwT  = ws + 511744;           // 65536
    uint*  Pl1    = (uint*)(ws + 577280);  // 131072
    uint*  Pl2    = (uint*)(ws + 708352);  // 131072
    float* nqin   = ws + 839424;           // 245760 (384 x 640)
    float* nrow   = ws + 1085184;          // 98304  (384 x 256)

    k_prep<<<896, 256, 0, stream>>>(tgt, qpos, ipw, ipb, opw, ojw, valw, l1w, l2w,
                                    qkv, opwT, ojwT, valwT, Pl1, Pl2);
    k_attn<<<128, 1024, 0, stream>>>(qkv, tgt, qpos, opwT, opb, n2w, n2b, ec,
                                     x1, nqin, refxy, lxly);
    k_lin<640><<<192, 256, 0, stream>>>(nqin, l0w, l0b, l0w, l0b, nrow, 256, 32);
    k_lin<256><<<288, 256, 0, stream>>>(nrow, offw, offb, aww, awb, offatr, 384, 48);
    k_sample<<<384, 1024, 0, stream>>>(offatr, refxy, vr, lxly, src, mask, valwT, valb, ca);
    k_tail<<<128, 1024, 0, stream>>>(ca, x1, ojwT, ojb, n1w, n1b, Pl1, l1b, Pl2, l2b, n3w, n3b, (float*)d_out);
}

// Round 4
// 275.820 us; speedup vs baseline: 1.0997x; 1.0997x over previous
//
#include <hip/hip_runtime.h>
#include <math.h>

// All inputs/outputs fp32 (verified R2).
// R10: k_sample per-point dedupe of 512 tap rows. 277.2us measured (best).
// R11 FAILED (+26us): splitting k_edge into k_attn + 2 GEMM launches — per-launch
// overhead + small-grid latency > streaming saved. Reverted.
// R12: R10 base + (a) k_sample level-major taps (dedupe scan confined to 128-tap
// level segment, 4x shorter), (b) k_edge phase-B register-prefetch double-buffer
// (next weight tile loaded into uint4 regs during current tile's compute, hiding
// the 14 serial L2 round-trips per block).

typedef unsigned int uint;

__device__ __forceinline__ float lo16(uint u) { return __uint_as_float(u << 16); }
__device__ __forceinline__ float hi16(uint u) { return __uint_as_float(u & 0xFFFF0000u); }
__device__ __forceinline__ uint bfr(float x) {  // fp32 -> bf16 bits, RNE
    uint u = __float_as_uint(x);
    return (u + 0x7FFFu + ((u >> 16) & 1u)) >> 16;
}

__device__ __forceinline__ float block_sum256w(float v, float* red) {
    int t = threadIdx.x;
    if (t < 256) red[t] = v;
    __syncthreads();
    for (int st = 128; st > 0; st >>= 1) {
        if (t < st) red[t] += red[t + st];
        __syncthreads();
    }
    float r = red[0]; __syncthreads();
    return r;
}

// ---- tiled GEMM unit (R4-verified): 64 rows x 8 outputs ----
template <int K, int MI, int MO>
__device__ void gemm_unit(const float* __restrict__ IN, const float* __restrict__ IN2,
                          const float* __restrict__ W, const float* __restrict__ B,
                          float* __restrict__ OUT, int O, int OG, int u, float* smem) {
    constexpr int KC = 128;
    constexpr int LDT = KC + 4;
    float* tile = smem;
    int og = u % OG, rg = u / OG;
    int o0 = og * 8, r0 = rg * 64;
    int t = threadIdx.x;
    int r = t & 63;
    int ol = __builtin_amdgcn_readfirstlane(t >> 6);
    int oa = o0 + ol, ob = o0 + 4 + ol;
    const float* Wa = W + (size_t)oa * K;
    const float* Wb = W + (size_t)ob * K;
    float Ba = B[oa], Bb = B[ob];
    float acca = 0.f, accb = 0.f;
    for (int c = 0; c < K / KC; c++) {
        for (int idx = t; idx < 64 * KC; idx += 256) {
            int rr = idx >> 7, ii = idx & (KC - 1);
            int row = r0 + rr, col = c * KC + ii;
            float v;
            if (MI == 0) {
                v = IN[(size_t)row * K + col];
            } else {
                float tv = IN[row * 256 + col];
                v = (o0 < 512) ? tv + IN2[row * 256 + col] : tv;
            }
            tile[rr * LDT + ii] = v;
        }
        __syncthreads();
        const float4* wa4 = (const float4*)(Wa + c * KC);
        const float4* wb4 = (const float4*)(Wb + c * KC);
        const float4* trow = (const float4*)(tile + r * LDT);
        #pragma unroll
        for (int i4 = 0; i4 < KC / 4; i4++) {
            float4 x4 = trow[i4];
            float4 a4 = wa4[i4];
            float4 b4 = wb4[i4];
            acca += x4.x * a4.x; acca += x4.y * a4.y;
            acca += x4.z * a4.z; acca += x4.w * a4.w;
            accb += x4.x * b4.x; accb += x4.y * b4.y;
            accb += x4.z * b4.z; accb += x4.w * b4.w;
        }
        __syncthreads();
    }
    acca += Ba; accb += Bb;
    if (MO == 2) {
        if (oa < 256) acca *= 0.17677669529663687f;
        if (ob < 256) accb *= 0.17677669529663687f;
    }
    OUT[(size_t)(r0 + r) * O + oa] = acca;
    OUT[(size_t)(r0 + r) * O + ob] = accb;
}

// ---- fp32 transpose unit: out[c*256 + r] = in[r][c] (R,C mult of 32) ----
__device__ void transpose_unit(const float* __restrict__ in, float* __restrict__ out,
                               int R, int C, int u, float* smem) {
    int TC = C >> 5;
    int tc = u % TC, tr = u / TC;
    int t = threadIdx.x;
    int lr = t >> 5, lc = t & 31;
    #pragma unroll
    for (int rr = 0; rr < 32; rr += 8)
        smem[(rr + lr) * 33 + lc] = in[(size_t)(tr * 32 + rr + lr) * C + tc * 32 + lc];
    __syncthreads();
    #pragma unroll
    for (int rr = 0; rr < 32; rr += 8)
        out[(size_t)(tc * 32 + rr + lr) * R + tr * 32 + lc] = smem[lc * 33 + rr + lr];
    __syncthreads();
}

// ---- transpose+bf16-pack: P[(k2)*S + F + r] = pack(in[r][2k2], in[r][2k2+1]) ----
__device__ void tpack_unit(const float* __restrict__ in, uint* __restrict__ P,
                           int C, int S, int F, int u, float* smem) {
    int TC = C >> 5;
    int tc = u % TC, tr = u / TC;
    int t = threadIdx.x;
    int lr = t >> 5, lc = t & 31;
    #pragma unroll
    for (int rr = 0; rr < 32; rr += 8)
        smem[(rr + lr) * 33 + lc] = in[(size_t)(tr * 32 + rr + lr) * C + tc * 32 + lc];
    __syncthreads();
    #pragma unroll
    for (int rep = 0; rep < 2; rep++) {
        int idx = rep * 256 + t;
        int c2 = idx >> 5, r = idx & 31;
        uint w0 = bfr(smem[r * 33 + 2 * c2]);
        uint w1 = bfr(smem[r * 33 + 2 * c2 + 1]);
        P[(size_t)(tc * 16 + c2) * S + F + tr * 32 + r] = (w1 << 16) | w0;
    }
    __syncthreads();
}

// ---------------- S1: qkv gemm + weight transposes/packs ----------------
// grid 1152, block 256
__global__ __launch_bounds__(256) void k_prep(const float* __restrict__ tgt,
                                              const float* __restrict__ qpos,
                                              const float* __restrict__ ipw,
                                              const float* __restrict__ ipb,
                                              const float* __restrict__ opw,
                                              const float* __restrict__ ojw,
                                              const float* __restrict__ valw,
                                              const float* __restrict__ l1w,
                                              const float* __restrict__ l2w,
                                              const float* __restrict__ l0w,
                                              const float* __restrict__ offw,
                                              const float* __restrict__ aww,
                                              float* __restrict__ qkv,
                                              float* __restrict__ opwT,
                                              float* __restrict__ ojwT,
                                              float* __restrict__ valwT,
                                              uint* __restrict__ Pl1,
                                              uint* __restrict__ Pl2,
                                              uint* __restrict__ Pl0,
                                              uint* __restrict__ Poaw) {
    __shared__ __align__(16) float smem[8448];
    int u = blockIdx.x;
    if (u < 192)       gemm_unit<256, 1, 2>(tgt, qpos, ipw, ipb, qkv, 768, 96, u, smem);
    else if (u < 256)  transpose_unit(opw, opwT, 256, 256, u - 192, smem);
    else if (u < 320)  transpose_unit(ojw, ojwT, 256, 256, u - 256, smem);
    else if (u < 384)  transpose_unit(valw, valwT, 256, 256, u - 320, smem);
    else if (u < 640)  tpack_unit(l1w, Pl1, 256, 1024, 0, u - 384, smem);
    else if (u < 896)  tpack_unit(l2w, Pl2, 1024, 256, 0, u - 640, smem);
    else if (u < 1056) tpack_unit(l0w, Pl0, 640, 256, 0, u - 896, smem);
    else if (u < 1120) tpack_unit(offw, Poaw, 256, 384, 0, u - 1056, smem);
    else               tpack_unit(aww, Poaw, 256, 384, 256, u - 1120, smem);
}

// ---- geometry for edge e, point j ----
__device__ __forceinline__ void edge_geom(const float* __restrict__ ec, int e, int j,
                                          float* pxs, float* pys,
                                          float& fminx, float& fminy,
                                          float& cxf, float& cyf) {
    float ax = ec[e * 4 + 0], ay = ec[e * 4 + 1];
    float bx = ec[e * 4 + 2], by = ec[e * 4 + 3];
    float dx = bx - ax, dy = by - ay;
    float tj = 0.5f * (float)j;
    float ptx = __fadd_rn(ax, __fmul_rn(tj, dx));
    float pty = __fadd_rn(ay, __fmul_rn(tj, dy));
    cxf = floorf(ptx); cyf = floorf(pty);
    int minx = max((int)cxf - 128, 0); if (minx + 256 > 2048) minx = 2048 - 256;
    int miny = max((int)cyf - 128, 0); if (miny + 256 > 2048) miny = 2048 - 256;
    fminx = (float)minx; fminy = (float)miny;
    float tlx, thx, tly, thy;
    if (dx == 0.f) { tlx = 0.f; thx = 1.f; }
    else { float u1 = (fminx - ax) / dx, u2 = (fminx + 256.f - ax) / dx; tlx = fminf(u1, u2); thx = fmaxf(u1, u2); }
    if (dy == 0.f) { tly = 0.f; thy = 1.f; }
    else { float u1 = (fminy - ay) / dy, u2 = (fminy + 256.f - ay) / dy; tly = fminf(u1, u2); thy = fmaxf(u1, u2); }
    float t0 = fmaxf(fmaxf(tlx, tly), 0.f);
    float t1 = fmaxf(fminf(fminf(thx, thy), 1.f), t0);
    pxs[0] = __fadd_rn(ax, __fmul_rn(t0, dx)); pys[0] = __fadd_rn(ay, __fmul_rn(t0, dy));
    pxs[1] = __fadd_rn(ax, __fmul_rn(t1, dx)); pys[1] = __fadd_rn(ay, __fmul_rn(t1, dy));
    pxs[2] = cxf; pys[2] = cyf;
}

// ---------------- S2: per-POINT (grid 384): attn(redundant)+oproj+norm2+pe+nq+offaw ----
__global__ __launch_bounds__(1024) void k_edge(const float* __restrict__ qkv,
                                               const float* __restrict__ tgt,
                                               const float* __restrict__ qpos,
                                               const float* __restrict__ opwT,
                                               const float* __restrict__ opb,
                                               const float* __restrict__ n2w,
                                               const float* __restrict__ n2b,
                                               const float* __restrict__ ec,
                                               const uint* __restrict__ Pl0,
                                               const float* __restrict__ l0b,
                                               const uint* __restrict__ Poaw,
                                               const float* __restrict__ offb,
                                               const float* __restrict__ awb,
                                               float* __restrict__ x1,
                                               float* __restrict__ offatr,
                                               float* __restrict__ refxy,
                                               int* __restrict__ lxly) {
    int n = blockIdx.x, t = threadIdx.x;
    int e = n / 3, j = n - e * 3;
    __shared__ __align__(16) float SH[14208];
    float* xq   = SH;
    float* sq   = SH + 256;
    float* sS   = SH + 512;
    float* smax = SH + 1536;
    float* ssum = SH + 1544;
    float* srow = SH + 1552;
    float* part = SH + 1808;
    float* red  = SH + 2832;
    float* pe    = SH + 256;    // phase B
    float* nrow  = SH + 640;
    float* partial = SH + 896;
    uint*  wt    = (uint*)(SH + 1920);
    // ---- attention (redundant across the 3 point-blocks of this edge) ----
    if (t < 256) sq[t] = qkv[e * 768 + t];
    __syncthreads();
    {
        int h = t >> 7, f = t & 127;
        const float* kf = qkv + f * 768 + 256 + h * 32;
        const float* qh = sq + h * 32;
        float s = 0.f;
        #pragma unroll 8
        for (int d = 0; d < 32; d++) s += qh[d] * kf[d];
        sS[t] = s;
    }
    __syncthreads();
    if (t < 8) {
        float m = -1e30f;
        for (int f = 0; f < 128; f++) m = fmaxf(m, sS[t * 128 + f]);
        smax[t] = m;
    }
    __syncthreads();
    sS[t] = __expf(sS[t] - smax[t >> 7]);
    __syncthreads();
    if (t < 8) {
        float s = 0.f;
        for (int f = 0; f < 128; f++) s += sS[t * 128 + f];
        ssum[t] = 1.f / s;
    }
    __syncthreads();
    {
        int o = t & 255, c = t >> 8, h = o >> 5, d = o & 31;
        float acc = 0.f;
        #pragma unroll 8
        for (int f = c * 32; f < c * 32 + 32; f++)
            acc += sS[h * 128 + f] * qkv[f * 768 + 512 + h * 32 + d];
        part[t] = acc;
    }
    __syncthreads();
    if (t < 256) srow[t] = (part[t] + part[256 + t] + part[512 + t] + part[768 + t]) * ssum[t >> 5];
    __syncthreads();
    // ---- oproj ----
    {
        int o = t & 255, c = t >> 8;
        float acc = 0.f;
        #pragma unroll 8
        for (int i = c * 64; i < c * 64 + 64; i++) acc += srow[i] * opwT[(size_t)i * 256 + o];
        part[t] = acc;
    }
    __syncthreads();
    // ---- norm2 -> x1 (j==0 only), xq ----
    {
        float acc = 0.f;
        if (t < 256) acc = part[t] + part[256 + t] + part[512 + t] + part[768 + t] + opb[t] + tgt[e * 256 + t];
        float mean = block_sum256w(acc, red) * (1.f / 256.f);
        float d0 = acc - mean;
        float var = block_sum256w((t < 256) ? d0 * d0 : 0.f, red) * (1.f / 256.f);
        if (t < 256) {
            float xln = d0 * rsqrtf(var + 1e-5f) * n2w[t] + n2b[t];
            if (j == 0) x1[e * 256 + t] = xln;
            xq[t] = xln + qpos[e * 256 + t];
        }
    }
    // ---- pos-encode: own point only (384 elems; aliases dead sq/sS) ----
    if (t < 384) {
        float pxs[3], pys[3], fmx, fmy, cxf, cyf;
        edge_geom(ec, e, j, pxs, pys, fmx, fmy, cxf, cyf);
        int jj = t >> 7, tt = t & 127, i = tt & 63, kk = i >> 1;
        float invd = __expf(-(float)kk * (9.210340371976184f / 32.f));  // 10000^(-kk/32)
        float vv = (tt < 64) ? pys[jj] : pxs[jj];
        float pp = vv * invd;
        pe[t] = (i & 1) ? __cosf(pp) : __sinf(pp);
    }
    if (t == 0) {
        float pxs[3], pys[3], fmx, fmy, cxf, cyf;
        edge_geom(ec, e, j, pxs, pys, fmx, fmy, cxf, cyf);
        refxy[n * 2 + 0] = (cxf - fmx) * (1.f / 256.f);
        refxy[n * 2 + 1] = (cyf - fmy) * (1.f / 256.f);
        lxly[n * 8 + 0] = (int)rintf(fmx * 0.125f);
        lxly[n * 8 + 1] = (int)rintf(fmx * 0.0625f);
        lxly[n * 8 + 2] = (int)rintf(fmx * 0.03125f);
        lxly[n * 8 + 3] = (int)rintf(fmx * 0.015625f);
        lxly[n * 8 + 4] = (int)rintf(fmy * 0.125f);
        lxly[n * 8 + 5] = (int)rintf(fmy * 0.0625f);
        lxly[n * 8 + 6] = (int)rintf(fmy * 0.03125f);
        lxly[n * 8 + 7] = (int)rintf(fmy * 0.015625f);
    }
    __syncthreads();
    // ---- nq: K=640, 256 outs; 10 tiles, register-prefetch double-buffered ----
    {
        int o = t & 255, kc = t >> 8;
        float acc = 0.f;
        uint4* d4 = (uint4*)wt;
        const uint4* s4 = (const uint4*)Pl0;
        uint4 pA = s4[t], pB = s4[1024 + t];
        for (int tk = 0; tk < 10; tk++) {
            d4[t] = pA;
            d4[1024 + t] = pB;
            __syncthreads();
            if (tk < 9) {
                const uint4* nx = (const uint4*)(Pl0 + (size_t)(tk + 1) * 8192);
                pA = nx[t]; pB = nx[1024 + t];
            }
            const float* inb = (tk < 4) ? (xq + tk * 64) : (pe + tk * 64 - 256);
            #pragma unroll
            for (int kk = 0; kk < 8; kk++) {
                uint u = wt[(kc * 8 + kk) * 256 + o];
                acc += inb[(kc * 8 + kk) * 2] * lo16(u);
                acc += inb[(kc * 8 + kk) * 2 + 1] * hi16(u);
            }
            __syncthreads();
        }
        partial[t] = acc;
    }
    __syncthreads();
    if (t < 256) nrow[t] = partial[t] + partial[256 + t] + partial[512 + t] + partial[768 + t] + l0b[t];
    __syncthreads();
    // ---- off+attw: K=256, O=384; 4 tiles, register-prefetch double-buffered ----
    {
        int o = t % 384, kc = t / 384;  // valid for t<768
        float acc = 0.f;
        uint4* d4 = (uint4*)wt;
        const uint4* s4 = (const uint4*)Poaw;
        uint4 pA = s4[t], pB = s4[1024 + t], pC = s4[2048 + t];
        for (int tk = 0; tk < 4; tk++) {
            d4[t] = pA;
            d4[1024 + t] = pB;
            d4[2048 + t] = pC;
            __syncthreads();
            if (tk < 3) {
                const uint4* nx = (const uint4*)(Poaw + (size_t)(tk + 1) * 12288);
                pA = nx[t]; pB = nx[1024 + t]; pC = nx[2048 + t];
            }
            if (t < 768) {
                const float* inb = nrow + tk * 64 + kc * 32;
                #pragma unroll
                for (int kk = 0; kk < 16; kk++) {
                    uint u = wt[(kc * 16 + kk) * 384 + o];
                    acc += inb[kk * 2] * lo16(u);
                    acc += inb[kk * 2 + 1] * hi16(u);
                }
            }
            __syncthreads();
        }
        if (t < 768) partial[t] = acc;
    }
    __syncthreads();
    if (t < 384) {
        float b = (t < 256) ? offb[t] : awb[t - 256];
        offatr[(size_t)n * 384 + t] = partial[t] + partial[384 + t] + b;
    }
}

// ---------------- S3: deformable sampling, per-point with tap dedupe ----------------
// grid N=384, block 1024. Taps indexed level-major: rows from different levels live
// in disjoint index ranges, so the first-occurrence scan stays within the 128-tap
// level segment.
__global__ __launch_bounds__(1024) void k_sample(const float* __restrict__ offatr,
                                                 const float* __restrict__ refxy,
                                                 const float* __restrict__ vr,
                                                 const int* __restrict__ lxly,
                                                 const float* __restrict__ src,
                                                 const unsigned char* __restrict__ mask,
                                                 const float* __restrict__ valwT,
                                                 const float* __restrict__ valb,
                                                 float* __restrict__ ca) {
    int n = blockIdx.x, t = threadIdx.x;
    __shared__ float sl[128];          // logits [h][16]
    __shared__ float sm[8], sinv[8];
    __shared__ float sw[512];          // tap weights
    __shared__ int   sg[512];          // tap global rows (-1 invalid)
    __shared__ int   lead[512];
    __shared__ int   rk[512];          // leader -> compact rank
    __shared__ int   ulist[512];       // rank -> global row
    __shared__ int   redi[256];
    __shared__ float uw[512 * 8];      // per-unique per-head weight (16 KB)
    __shared__ float agg[8 * 256];     // aggregated value rows per head (8 KB)
    __shared__ float pcs[64];
    __shared__ float pagg[1024];

    if (t < 128) sl[t] = offatr[(size_t)n * 384 + 256 + t];
    #pragma unroll
    for (int z = 0; z < 4; z++) uw[z * 1024 + t] = 0.f;
    __syncthreads();
    if (t < 8) {
        float m = -1e30f;
        for (int i = 0; i < 16; i++) m = fmaxf(m, sl[t * 16 + i]);
        float s = 0.f;
        for (int i = 0; i < 16; i++) s += __expf(sl[t * 16 + i] - m);
        sm[t] = m; sinv[t] = 1.f / s;
    }
    __syncthreads();
    // ---- compute all 512 taps (level-major: t = l*128 + h*16 + pp*4 + tap) ----
    if (t < 512) {
        int l = t >> 7, rem = t & 127;
        int h = rem >> 4, pp = (rem >> 2) & 3, tap = t & 3;
        int s = 32 >> l, wl = 256 >> l;
        const int img_starts[4] = {0, 65536, 81920, 86016};
        float a = __expf(sl[h * 16 + l * 4 + pp] - sm[h]) * sinv[h];
        float slv = (float)s;
        float gx = refxy[n * 2 + 0] * vr[l * 2 + 0] + offatr[(size_t)n * 384 + h * 32 + l * 8 + pp * 2 + 0] / slv;
        float gy = refxy[n * 2 + 1] * vr[l * 2 + 1] + offatr[(size_t)n * 384 + h * 32 + l * 8 + pp * 2 + 1] / slv;
        float px = gx * slv - 0.5f, py = gy * slv - 0.5f;
        float x0 = floorf(px), y0 = floorf(py);
        float fx = px - x0, fy = py - y0;
        int xi = (int)x0 + (tap & 1), yi = (int)y0 + (tap >> 1);
        float wtt = ((tap & 1) ? fx : (1.f - fx)) * ((tap >> 1) ? fy : (1.f - fy));
        int g = -1;
        if (xi >= 0 && xi < s && yi >= 0 && yi < s) {
            int col = lxly[n * 8 + l] + xi;
            int row = lxly[n * 8 + 4 + l] + yi;
            g = img_starts[l] + row * wl + col;
            if (mask[g]) g = -1;  // masked rows zeroed (incl. bias)
        }
        sw[t] = a * wtt;
        sg[t] = g;
    }
    __syncthreads();
    // ---- first-occurrence dedupe (within level segment only) ----
    int fi = -1;
    if (t < 512) {
        int g = sg[t];
        if (g >= 0) {
            fi = t;
            int base = t & ~127;  // level segment start
            for (int jj = base; jj < t; jj++) if (sg[jj] == g) { fi = jj; break; }
        }
        lead[t] = (fi == t) ? 1 : 0;
    }
    __syncthreads();
    // leader ranks (deterministic compaction) + parallel count of leaders
    if (t < 512 && fi == t) {
        int r = 0;
        for (int jj = 0; jj < t; jj++) r += lead[jj];
        rk[t] = r;
        ulist[r] = sg[t];
    }
    if (t < 256) redi[t] = lead[t] + lead[t + 256];
    __syncthreads();
    for (int st = 128; st > 0; st >>= 1) {
        if (t < st) redi[t] += redi[t + st];
        __syncthreads();
    }
    // ---- accumulate per-unique per-head weights ----
    if (t < 512 && fi >= 0) {
        int h = (t >> 4) & 7;
        atomicAdd(&uw[rk[fi] * 8 + h], sw[t]);
    }
    __syncthreads();
    int U = redi[0];
    // ---- main gather: each unique row read once, applied to 2 heads/thread ----
    {
        int ch = t & 255, q = t >> 8;
        float a0 = 0.f, a1 = 0.f;
        for (int u = 0; u < U; u++) {
            int g = ulist[u];
            float v = src[(size_t)g * 256 + ch];
            a0 += uw[u * 8 + 2 * q] * v;
            a1 += uw[u * 8 + 2 * q + 1] * v;
        }
        agg[(2 * q) * 256 + ch] = a0;
        agg[(2 * q + 1) * 256 + ch] = a1;
    }
    // csum partials (deterministic)
    if (t < 64) {
        int h = t >> 3, p = t & 7;
        float s = 0.f;
        for (int u = p; u < U; u += 8) s += uw[u * 8 + h];
        pcs[t] = s;
    }
    __syncthreads();
    // ---- fused value projection: out[h][32] ----
    {
        int h = t >> 7, rem = t & 127, o = rem & 31, kc = rem >> 5;
        const float* ag = agg + h * 256 + kc * 64;
        const float* w = valwT + (size_t)(kc * 64) * 256 + h * 32 + o;
        float pv = 0.f;
        #pragma unroll 8
        for (int i = 0; i < 64; i++) pv += ag[i] * w[(size_t)i * 256];
        pagg[t] = pv;
    }
    __syncthreads();
    if (t < 256) {
        int h = t >> 5, o = t & 31;
        float cs = pcs[h * 8 + 0] + pcs[h * 8 + 1] + pcs[h * 8 + 2] + pcs[h * 8 + 3]
                 + pcs[h * 8 + 4] + pcs[h * 8 + 5] + pcs[h * 8 + 6] + pcs[h * 8 + 7];
        float r = pagg[h * 128 + o] + pagg[h * 128 + 32 + o] + pagg[h * 128 + 64 + o] + pagg[h * 128 + 96 + o];
        ca[(size_t)n * 256 + h * 32 + o] = r + cs * valb[h * 32 + o];
    }
}

// ---------------- S4: pool + oproj + norm1 + ffn1 + ffn2 + norm3 ----------------
// grid 128 (per edge), block 1024; ffn weights bf16-packed
__global__ __launch_bounds__(1024) void k_tail(const float* __restrict__ ca,
                                               const float* __restrict__ x1,
                                               const float* __restrict__ ojwT,
                                               const float* __restrict__ ojb,
                                               const float* __restrict__ n1w,
                                               const float* __restrict__ n1b,
                                               const uint* __restrict__ Pl1,
                                               const float* __restrict__ l1b,
                                               const uint* __restrict__ Pl2,
                                               const float* __restrict__ l2b,
                                               const float* __restrict__ n3w,
                                               const float* __restrict__ n3b,
                                               float* __restrict__ out) {
    int e = blockIdx.x, t = threadIdx.x;
    __shared__ float row[256], red[256], x2s[256], h1s[1024], part[1024];
    if (t < 256)
        row[t] = (ca[(3 * e) * 256 + t] + ca[(3 * e + 1) * 256 + t] + ca[(3 * e + 2) * 256 + t]) * (1.f / 3.f);
    __syncthreads();
    // oproj: 256 outputs x 4 chunks of 64
    {
        int o = t & 255, c = t >> 8;
        float acc = 0.f;
        #pragma unroll 8
        for (int i = c * 64; i < c * 64 + 64; i++) acc += row[i] * ojwT[(size_t)i * 256 + o];
        part[t] = acc;
    }
    __syncthreads();
    // norm1
    {
        float acc = 0.f;
        if (t < 256) acc = part[t] + part[256 + t] + part[512 + t] + part[768 + t] + ojb[t] + x1[e * 256 + t];
        float mean = block_sum256w(acc, red) * (1.f / 256.f);
        float d0 = acc - mean;
        float var = block_sum256w((t < 256) ? d0 * d0 : 0.f, red) * (1.f / 256.f);
        if (t < 256) x2s[t] = d0 * rsqrtf(var + 1e-5f) * n1w[t] + n1b[t];
    }
    __syncthreads();
    // ffn1: one output per thread, packed K=256 (128 uints)
    {
        float acc = l1b[t];
        #pragma unroll 8
        for (int k2 = 0; k2 < 128; k2++) {
            uint u = Pl1[(size_t)k2 * 1024 + t];
            acc += x2s[2 * k2] * lo16(u);
            acc += x2s[2 * k2 + 1] * hi16(u);
        }
        h1s[t] = fmaxf(acc, 0.f);
    }
    __syncthreads();
    // ffn2: 256 outputs x 4 chunks of 128 packed
    {
        int o = t & 255, c = t >> 8;
        float acc = 0.f;
        #pragma unroll 8
        for (int k2 = c * 128; k2 < c * 128 + 128; k2++) {
            uint u = Pl2[(size_t)k2 * 256 + o];
            acc += h1s[2 * k2] * lo16(u);
            acc += h1s[2 * k2 + 1] * hi16(u);
        }
        part[t] = acc;
    }
    __syncthreads();
    // norm3 -> out
    {
        float acc = 0.f;
        if (t < 256) acc = part[t] + part[256 + t] + part[512 + t] + part[768 + t] + l2b[t] + x2s[t];
        float mean = block_sum256w(acc, red) * (1.f / 256.f);
        float d0 = acc - mean;
        float var = block_sum256w((t < 256) ? d0 * d0 : 0.f, red) * (1.f / 256.f);
        if (t < 256) out[e * 256 + t] = d0 * rsqrtf(var + 1e-5f) * n3w[t] + n3b[t];
    }
}

extern "C" void kernel_launch(void* const* d_in, const int* in_sizes, int n_in,
                              void* d_out, int out_size, void* d_ws, size_t ws_size,
                              hipStream_t stream) {
    (void)in_sizes; (void)n_in; (void)out_size; (void)ws_size;
    const float* tgt  = (const float*)d_in[0];
    const float* qpos = (const float*)d_in[1];
    const float* ec   = (const float*)d_in[2];
    const float* src  = (const float*)d_in[3];
    const unsigned char* mask = (const unsigned char*)d_in[4];
    const float* vr   = (const float*)d_in[5];
    const float* ipw  = (const float*)d_in[6];
    const float* ipb  = (const float*)d_in[7];
    const float* opw  = (const float*)d_in[8];
    const float* opb  = (const float*)d_in[9];
    const float* n1w  = (const float*)d_in[10];
    const float* n1b  = (const float*)d_in[11];
    const float* n2w  = (const float*)d_in[12];
    const float* n2b  = (const float*)d_in[13];
    const float* n3w  = (const float*)d_in[14];
    const float* n3b  = (const float*)d_in[15];
    const float* l0w  = (const float*)d_in[16];
    const float* l0b  = (const float*)d_in[17];
    const float* l1w  = (const float*)d_in[18];
    const float* l1b  = (const float*)d_in[19];
    const float* l2w  = (const float*)d_in[20];
    const float* l2b  = (const float*)d_in[21];
    const float* offw = (const float*)d_in[22];
    const float* offb = (const float*)d_in[23];
    const float* aww  = (const float*)d_in[24];
    const float* awb  = (const float*)d_in[25];
    const float* valw = (const float*)d_in[26];
    const float* valb = (const float*)d_in[27];
    const float* ojw  = (const float*)d_in[28];
    const float* ojb  = (const float*)d_in[29];

    float* ws     = (float*)d_ws;
    float* qkv    = ws;                   // 98304
    float* x1     = ws + 98304;           // 32768
    float* offatr = ws + 131072;          // 147456
    float* ca     = ws + 278528;          // 98304
    float* refxy  = ws + 376832;          // 768
    int*   lxly   = (int*)(ws + 377600);  // 3072
    float* opwT   = ws + 380672;          // 65536
    float* ojwT   = ws + 446208;          // 65536
    float* valwT  = ws + 511744;          // 65536
    uint*  Pl1    = (uint*)(ws + 577280); // 131072
    uint*  Pl2    = (uint*)(ws + 708352); // 131072
    uint*  Pl0    = (uint*)(ws + 839424); // 81920
    uint*  Poaw   = (uint*)(ws + 921344); // 49152

    k_prep<<<1152, 256, 0, stream>>>(tgt, qpos, ipw, ipb, opw, ojw, valw, l1w, l2w,
                                     l0w, offw, aww,
                                     qkv, opwT, ojwT, valwT, Pl1, Pl2, Pl0, Poaw);
    k_edge<<<384, 1024, 0, stream>>>(qkv, tgt, qpos, opwT, opb, n2w, n2b, ec,
                                     Pl0, l0b, Poaw, offb, awb,
                                     x1, offatr, refxy, lxly);
    k_sample<<<384, 1024, 0, stream>>>(offatr, refxy, vr, lxly, src, mask, valwT, valb, ca);
    k_tail<<<128, 1024, 0, stream>>>(ca, x1, ojwT, ojb, n1w, n1b, Pl1, l1b, Pl2, l2b, n3w, n3b, (float*)d_out);
}

// Round 5
// 263.704 us; speedup vs baseline: 1.1502x; 1.0459x over previous
//
#include <hip/hip_runtime.h>
#include <math.h>

// All inputs/outputs fp32 (verified R2).
// R10: k_sample per-point dedupe of 512 tap rows. 277.2us.
// R11 FAILED (+26us): k_edge split into 3 launches — launch overhead dominated.
// R12 NEUTRAL (-1.4us): reg-prefetch dbuf + shorter dedupe scan -> latency wasn't
// the bottleneck. 275.8us.
// R13: de-serialize. k_edge phase-B LDS weight staging has ZERO intra-block reuse
// (each packed weight read by exactly 1 thread, already coalesced) -> direct L2
// reads, 28 barriers -> 3. Softmax + norm tree-reductions -> 64-lane shfl_xor
// reductions (k_edge ~56 -> ~14 barriers/block; k_tail 60 -> 12). k_sample leader
// ranks via __ballot prefix (removes 511-iter serial loops).

typedef unsigned int uint;

__device__ __forceinline__ float lo16(uint u) { return __uint_as_float(u << 16); }
__device__ __forceinline__ float hi16(uint u) { return __uint_as_float(u & 0xFFFF0000u); }
__device__ __forceinline__ uint bfr(float x) {  // fp32 -> bf16 bits, RNE
    uint u = __float_as_uint(x);
    return (u + 0x7FFFu + ((u >> 16) & 1u)) >> 16;
}

// shfl-based block sum over threads t<256 (others must pass 0). 2 barriers.
__device__ __forceinline__ float block_sum256f(float v, float* red) {
    int t = threadIdx.x;
    __syncthreads();  // protect red reuse across back-to-back calls
    #pragma unroll
    for (int off = 32; off; off >>= 1) v += __shfl_xor(v, off);
    if (t < 256 && (t & 63) == 0) red[t >> 6] = v;
    __syncthreads();
    return red[0] + red[1] + red[2] + red[3];
}

// ---- tiled GEMM unit (R4-verified): 64 rows x 8 outputs ----
template <int K, int MI, int MO>
__device__ void gemm_unit(const float* __restrict__ IN, const float* __restrict__ IN2,
                          const float* __restrict__ W, const float* __restrict__ B,
                          float* __restrict__ OUT, int O, int OG, int u, float* smem) {
    constexpr int KC = 128;
    constexpr int LDT = KC + 4;
    float* tile = smem;
    int og = u % OG, rg = u / OG;
    int o0 = og * 8, r0 = rg * 64;
    int t = threadIdx.x;
    int r = t & 63;
    int ol = __builtin_amdgcn_readfirstlane(t >> 6);
    int oa = o0 + ol, ob = o0 + 4 + ol;
    const float* Wa = W + (size_t)oa * K;
    const float* Wb = W + (size_t)ob * K;
    float Ba = B[oa], Bb = B[ob];
    float acca = 0.f, accb = 0.f;
    for (int c = 0; c < K / KC; c++) {
        for (int idx = t; idx < 64 * KC; idx += 256) {
            int rr = idx >> 7, ii = idx & (KC - 1);
            int row = r0 + rr, col = c * KC + ii;
            float v;
            if (MI == 0) {
                v = IN[(size_t)row * K + col];
            } else {
                float tv = IN[row * 256 + col];
                v = (o0 < 512) ? tv + IN2[row * 256 + col] : tv;
            }
            tile[rr * LDT + ii] = v;
        }
        __syncthreads();
        const float4* wa4 = (const float4*)(Wa + c * KC);
        const float4* wb4 = (const float4*)(Wb + c * KC);
        const float4* trow = (const float4*)(tile + r * LDT);
        #pragma unroll
        for (int i4 = 0; i4 < KC / 4; i4++) {
            float4 x4 = trow[i4];
            float4 a4 = wa4[i4];
            float4 b4 = wb4[i4];
            acca += x4.x * a4.x; acca += x4.y * a4.y;
            acca += x4.z * a4.z; acca += x4.w * a4.w;
            accb += x4.x * b4.x; accb += x4.y * b4.y;
            accb += x4.z * b4.z; accb += x4.w * b4.w;
        }
        __syncthreads();
    }
    acca += Ba; accb += Bb;
    if (MO == 2) {
        if (oa < 256) acca *= 0.17677669529663687f;
        if (ob < 256) accb *= 0.17677669529663687f;
    }
    OUT[(size_t)(r0 + r) * O + oa] = acca;
    OUT[(size_t)(r0 + r) * O + ob] = accb;
}

// ---- fp32 transpose unit: out[c*256 + r] = in[r][c] (R,C mult of 32) ----
__device__ void transpose_unit(const float* __restrict__ in, float* __restrict__ out,
                               int R, int C, int u, float* smem) {
    int TC = C >> 5;
    int tc = u % TC, tr = u / TC;
    int t = threadIdx.x;
    int lr = t >> 5, lc = t & 31;
    #pragma unroll
    for (int rr = 0; rr < 32; rr += 8)
        smem[(rr + lr) * 33 + lc] = in[(size_t)(tr * 32 + rr + lr) * C + tc * 32 + lc];
    __syncthreads();
    #pragma unroll
    for (int rr = 0; rr < 32; rr += 8)
        out[(size_t)(tc * 32 + rr + lr) * R + tr * 32 + lc] = smem[lc * 33 + rr + lr];
    __syncthreads();
}

// ---- transpose+bf16-pack: P[(k2)*S + F + r] = pack(in[r][2k2], in[r][2k2+1]) ----
__device__ void tpack_unit(const float* __restrict__ in, uint* __restrict__ P,
                           int C, int S, int F, int u, float* smem) {
    int TC = C >> 5;
    int tc = u % TC, tr = u / TC;
    int t = threadIdx.x;
    int lr = t >> 5, lc = t & 31;
    #pragma unroll
    for (int rr = 0; rr < 32; rr += 8)
        smem[(rr + lr) * 33 + lc] = in[(size_t)(tr * 32 + rr + lr) * C + tc * 32 + lc];
    __syncthreads();
    #pragma unroll
    for (int rep = 0; rep < 2; rep++) {
        int idx = rep * 256 + t;
        int c2 = idx >> 5, r = idx & 31;
        uint w0 = bfr(smem[r * 33 + 2 * c2]);
        uint w1 = bfr(smem[r * 33 + 2 * c2 + 1]);
        P[(size_t)(tc * 16 + c2) * S + F + tr * 32 + r] = (w1 << 16) | w0;
    }
    __syncthreads();
}

// ---------------- S1: qkv gemm + weight transposes/packs ----------------
// grid 1152, block 256
__global__ __launch_bounds__(256) void k_prep(const float* __restrict__ tgt,
                                              const float* __restrict__ qpos,
                                              const float* __restrict__ ipw,
                                              const float* __restrict__ ipb,
                                              const float* __restrict__ opw,
                                              const float* __restrict__ ojw,
                                              const float* __restrict__ valw,
                                              const float* __restrict__ l1w,
                                              const float* __restrict__ l2w,
                                              const float* __restrict__ l0w,
                                              const float* __restrict__ offw,
                                              const float* __restrict__ aww,
                                              float* __restrict__ qkv,
                                              float* __restrict__ opwT,
                                              float* __restrict__ ojwT,
                                              float* __restrict__ valwT,
                                              uint* __restrict__ Pl1,
                                              uint* __restrict__ Pl2,
                                              uint* __restrict__ Pl0,
                                              uint* __restrict__ Poaw) {
    __shared__ __align__(16) float smem[8448];
    int u = blockIdx.x;
    if (u < 192)       gemm_unit<256, 1, 2>(tgt, qpos, ipw, ipb, qkv, 768, 96, u, smem);
    else if (u < 256)  transpose_unit(opw, opwT, 256, 256, u - 192, smem);
    else if (u < 320)  transpose_unit(ojw, ojwT, 256, 256, u - 256, smem);
    else if (u < 384)  transpose_unit(valw, valwT, 256, 256, u - 320, smem);
    else if (u < 640)  tpack_unit(l1w, Pl1, 256, 1024, 0, u - 384, smem);
    else if (u < 896)  tpack_unit(l2w, Pl2, 1024, 256, 0, u - 640, smem);
    else if (u < 1056) tpack_unit(l0w, Pl0, 640, 256, 0, u - 896, smem);
    else if (u < 1120) tpack_unit(offw, Poaw, 256, 384, 0, u - 1056, smem);
    else               tpack_unit(aww, Poaw, 256, 384, 256, u - 1120, smem);
}

// ---- geometry for edge e, point j ----
__device__ __forceinline__ void edge_geom(const float* __restrict__ ec, int e, int j,
                                          float* pxs, float* pys,
                                          float& fminx, float& fminy,
                                          float& cxf, float& cyf) {
    float ax = ec[e * 4 + 0], ay = ec[e * 4 + 1];
    float bx = ec[e * 4 + 2], by = ec[e * 4 + 3];
    float dx = bx - ax, dy = by - ay;
    float tj = 0.5f * (float)j;
    float ptx = __fadd_rn(ax, __fmul_rn(tj, dx));
    float pty = __fadd_rn(ay, __fmul_rn(tj, dy));
    cxf = floorf(ptx); cyf = floorf(pty);
    int minx = max((int)cxf - 128, 0); if (minx + 256 > 2048) minx = 2048 - 256;
    int miny = max((int)cyf - 128, 0); if (miny + 256 > 2048) miny = 2048 - 256;
    fminx = (float)minx; fminy = (float)miny;
    float tlx, thx, tly, thy;
    if (dx == 0.f) { tlx = 0.f; thx = 1.f; }
    else { float u1 = (fminx - ax) / dx, u2 = (fminx + 256.f - ax) / dx; tlx = fminf(u1, u2); thx = fmaxf(u1, u2); }
    if (dy == 0.f) { tly = 0.f; thy = 1.f; }
    else { float u1 = (fminy - ay) / dy, u2 = (fminy + 256.f - ay) / dy; tly = fminf(u1, u2); thy = fmaxf(u1, u2); }
    float t0 = fmaxf(fmaxf(tlx, tly), 0.f);
    float t1 = fmaxf(fminf(fminf(thx, thy), 1.f), t0);
    pxs[0] = __fadd_rn(ax, __fmul_rn(t0, dx)); pys[0] = __fadd_rn(ay, __fmul_rn(t0, dy));
    pxs[1] = __fadd_rn(ax, __fmul_rn(t1, dx)); pys[1] = __fadd_rn(ay, __fmul_rn(t1, dy));
    pxs[2] = cxf; pys[2] = cyf;
}

// ---------------- S2: per-POINT (grid 384): attn(redundant)+oproj+norm2+pe+nq+offaw ----
// LDS (floats): xq@0(256) sq@256(256) sS@512(1024) wred@1536(16) ssum@1552(8)
//   srow@1560(256) part@1824(1024) red@2848(8)
// phase B aliases: pe@256(384) nrow@640(256) partial@896(1024)
__global__ __launch_bounds__(1024) void k_edge(const float* __restrict__ qkv,
                                               const float* __restrict__ tgt,
                                               const float* __restrict__ qpos,
                                               const float* __restrict__ opwT,
                                               const float* __restrict__ opb,
                                               const float* __restrict__ n2w,
                                               const float* __restrict__ n2b,
                                               const float* __restrict__ ec,
                                               const uint* __restrict__ Pl0,
                                               const float* __restrict__ l0b,
                                               const uint* __restrict__ Poaw,
                                               const float* __restrict__ offb,
                                               const float* __restrict__ awb,
                                               float* __restrict__ x1,
                                               float* __restrict__ offatr,
                                               float* __restrict__ refxy,
                                               int* __restrict__ lxly) {
    int n = blockIdx.x, t = threadIdx.x;
    int e = n / 3, j = n - e * 3;
    __shared__ __align__(16) float SH[2880];
    float* xq   = SH;
    float* sq   = SH + 256;
    float* sS   = SH + 512;
    float* wred = SH + 1536;
    float* ssum = SH + 1552;
    float* srow = SH + 1560;
    float* part = SH + 1824;
    float* red  = SH + 2848;
    float* pe      = SH + 256;   // phase B
    float* nrow    = SH + 640;
    float* partial = SH + 896;
    // ---- attention (redundant across the 3 point-blocks of this edge) ----
    if (t < 256) sq[t] = qkv[e * 768 + t];
    __syncthreads();
    int h = t >> 7;
    {
        int f = t & 127;
        const float* kf = qkv + f * 768 + 256 + h * 32;
        const float* qh = sq + h * 32;
        float s = 0.f;
        #pragma unroll 8
        for (int d = 0; d < 32; d++) s += qh[d] * kf[d];
        // wave max (each wave is a single h; 2 waves per h)
        float m = s;
        #pragma unroll
        for (int off = 32; off; off >>= 1) m = fmaxf(m, __shfl_xor(m, off));
        if ((t & 63) == 0) wred[t >> 6] = m;
        __syncthreads();
        float hm = fmaxf(wred[2 * h], wred[2 * h + 1]);
        float ev = __expf(s - hm);
        sS[t] = ev;
        float su = ev;
        #pragma unroll
        for (int off = 32; off; off >>= 1) su += __shfl_xor(su, off);
        if ((t & 63) == 0) wred[t >> 6] = su;
        __syncthreads();
        if (t < 8) ssum[t] = 1.f / (wred[2 * t] + wred[2 * t + 1]);
    }
    // ---- PV ----
    {
        int o = t & 255, c = t >> 8, hh = o >> 5, d = o & 31;
        float acc = 0.f;
        #pragma unroll 8
        for (int f = c * 32; f < c * 32 + 32; f++)
            acc += sS[hh * 128 + f] * qkv[f * 768 + 512 + hh * 32 + d];
        part[t] = acc;
    }
    __syncthreads();
    if (t < 256) srow[t] = (part[t] + part[256 + t] + part[512 + t] + part[768 + t]) * ssum[t >> 5];
    __syncthreads();
    // ---- oproj ----
    {
        int o = t & 255, c = t >> 8;
        float acc = 0.f;
        #pragma unroll 8
        for (int i = c * 64; i < c * 64 + 64; i++) acc += srow[i] * opwT[(size_t)i * 256 + o];
        part[t] = acc;
    }
    __syncthreads();
    // ---- norm2 -> x1 (j==0 only), xq ----
    {
        float acc = 0.f;
        if (t < 256) acc = part[t] + part[256 + t] + part[512 + t] + part[768 + t] + opb[t] + tgt[e * 256 + t];
        float mean = block_sum256f(acc, red) * (1.f / 256.f);
        float d0 = acc - mean;
        float var = block_sum256f((t < 256) ? d0 * d0 : 0.f, red) * (1.f / 256.f);
        if (t < 256) {
            float xln = d0 * rsqrtf(var + 1e-5f) * n2w[t] + n2b[t];
            if (j == 0) x1[e * 256 + t] = xln;
            xq[t] = xln + qpos[e * 256 + t];
        }
    }
    // ---- pos-encode: own point (384 elems; aliases dead sq/sS) ----
    if (t < 384) {
        float pxs[3], pys[3], fmx, fmy, cxf, cyf;
        edge_geom(ec, e, j, pxs, pys, fmx, fmy, cxf, cyf);
        int jj = t >> 7, tt = t & 127, i = tt & 63, kk = i >> 1;
        float invd = __expf(-(float)kk * (9.210340371976184f / 32.f));  // 10000^(-kk/32)
        float vv = (tt < 64) ? pys[jj] : pxs[jj];
        float pp = vv * invd;
        pe[t] = (i & 1) ? __cosf(pp) : __sinf(pp);
    }
    if (t == 0) {
        float pxs[3], pys[3], fmx, fmy, cxf, cyf;
        edge_geom(ec, e, j, pxs, pys, fmx, fmy, cxf, cyf);
        refxy[n * 2 + 0] = (cxf - fmx) * (1.f / 256.f);
        refxy[n * 2 + 1] = (cyf - fmy) * (1.f / 256.f);
        lxly[n * 8 + 0] = (int)rintf(fmx * 0.125f);
        lxly[n * 8 + 1] = (int)rintf(fmx * 0.0625f);
        lxly[n * 8 + 2] = (int)rintf(fmx * 0.03125f);
        lxly[n * 8 + 3] = (int)rintf(fmx * 0.015625f);
        lxly[n * 8 + 4] = (int)rintf(fmy * 0.125f);
        lxly[n * 8 + 5] = (int)rintf(fmy * 0.0625f);
        lxly[n * 8 + 6] = (int)rintf(fmy * 0.03125f);
        lxly[n * 8 + 7] = (int)rintf(fmy * 0.015625f);
    }
    __syncthreads();
    // ---- nq: K=640, 256 outs; direct L2 reads (no intra-block weight reuse) ----
    {
        int o = t & 255, kc = t >> 8;
        float acc = 0.f;
        for (int tk = 0; tk < 10; tk++) {
            const float* inb = (tk < 4) ? (xq + tk * 64) : (pe + tk * 64 - 256);
            const uint* P = Pl0 + (size_t)tk * 8192 + (size_t)(kc * 8) * 256 + o;
            #pragma unroll
            for (int kk = 0; kk < 8; kk++) {
                uint u = P[kk * 256];
                acc += inb[(kc * 8 + kk) * 2] * lo16(u);
                acc += inb[(kc * 8 + kk) * 2 + 1] * hi16(u);
            }
        }
        partial[t] = acc;
    }
    __syncthreads();
    if (t < 256) nrow[t] = partial[t] + partial[256 + t] + partial[512 + t] + partial[768 + t] + l0b[t];
    __syncthreads();
    // ---- off+attw: K=256, O=384; direct L2 reads ----
    if (t < 768) {
        int o = t % 384, kc = t / 384;
        float acc = 0.f;
        for (int tk = 0; tk < 4; tk++) {
            const float* inb = nrow + tk * 64 + kc * 32;
            const uint* P = Poaw + (size_t)tk * 12288 + (size_t)(kc * 16) * 384 + o;
            #pragma unroll
            for (int kk = 0; kk < 16; kk++) {
                uint u = P[kk * 384];
                acc += inb[kk * 2] * lo16(u);
                acc += inb[kk * 2 + 1] * hi16(u);
            }
        }
        partial[t] = acc;
    }
    __syncthreads();
    if (t < 384) {
        float b = (t < 256) ? offb[t] : awb[t - 256];
        offatr[(size_t)n * 384 + t] = partial[t] + partial[384 + t] + b;
    }
}

// ---------------- S3: deformable sampling, per-point with tap dedupe ----------------
// grid N=384, block 1024. Level-major taps; ballot-based leader ranks.
__global__ __launch_bounds__(1024) void k_sample(const float* __restrict__ offatr,
                                                 const float* __restrict__ refxy,
                                                 const float* __restrict__ vr,
                                                 const int* __restrict__ lxly,
                                                 const float* __restrict__ src,
                                                 const unsigned char* __restrict__ mask,
                                                 const float* __restrict__ valwT,
                                                 const float* __restrict__ valb,
                                                 float* __restrict__ ca) {
    int n = blockIdx.x, t = threadIdx.x;
    __shared__ float sl[128];          // logits [h][16]
    __shared__ float sm[8], sinv[8];
    __shared__ float sw[512];          // tap weights
    __shared__ int   sg[512];          // tap global rows (-1 invalid)
    __shared__ int   rk[512];          // leader -> compact rank
    __shared__ int   ulist[512];       // rank -> global row
    __shared__ int   wtot[16];
    __shared__ float uw[512 * 8];      // per-unique per-head weight (16 KB)
    __shared__ float agg[8 * 256];     // aggregated value rows per head (8 KB)
    __shared__ float pcs[64];
    __shared__ float pagg[1024];

    if (t < 128) sl[t] = offatr[(size_t)n * 384 + 256 + t];
    #pragma unroll
    for (int z = 0; z < 4; z++) uw[z * 1024 + t] = 0.f;
    __syncthreads();
    if (t < 8) {
        float m = -1e30f;
        for (int i = 0; i < 16; i++) m = fmaxf(m, sl[t * 16 + i]);
        float s = 0.f;
        for (int i = 0; i < 16; i++) s += __expf(sl[t * 16 + i] - m);
        sm[t] = m; sinv[t] = 1.f / s;
    }
    __syncthreads();
    // ---- compute all 512 taps (level-major: t = l*128 + h*16 + pp*4 + tap) ----
    if (t < 512) {
        int l = t >> 7, rem = t & 127;
        int h = rem >> 4, pp = (rem >> 2) & 3, tap = t & 3;
        int s = 32 >> l, wl = 256 >> l;
        const int img_starts[4] = {0, 65536, 81920, 86016};
        float a = __expf(sl[h * 16 + l * 4 + pp] - sm[h]) * sinv[h];
        float slv = (float)s;
        float gx = refxy[n * 2 + 0] * vr[l * 2 + 0] + offatr[(size_t)n * 384 + h * 32 + l * 8 + pp * 2 + 0] / slv;
        float gy = refxy[n * 2 + 1] * vr[l * 2 + 1] + offatr[(size_t)n * 384 + h * 32 + l * 8 + pp * 2 + 1] / slv;
        float px = gx * slv - 0.5f, py = gy * slv - 0.5f;
        float x0 = floorf(px), y0 = floorf(py);
        float fx = px - x0, fy = py - y0;
        int xi = (int)x0 + (tap & 1), yi = (int)y0 + (tap >> 1);
        float wtt = ((tap & 1) ? fx : (1.f - fx)) * ((tap >> 1) ? fy : (1.f - fy));
        int g = -1;
        if (xi >= 0 && xi < s && yi >= 0 && yi < s) {
            int col = lxly[n * 8 + l] + xi;
            int row = lxly[n * 8 + 4 + l] + yi;
            g = img_starts[l] + row * wl + col;
            if (mask[g]) g = -1;  // masked rows zeroed (incl. bias)
        }
        sw[t] = a * wtt;
        sg[t] = g;
    }
    __syncthreads();
    // ---- first-occurrence dedupe (within 128-tap level segment) ----
    int fi = -1;
    if (t < 512) {
        int g = sg[t];
        if (g >= 0) {
            fi = t;
            int base = t & ~127;  // level segment start
            for (int jj = base; jj < t; jj++) if (sg[jj] == g) { fi = jj; break; }
        }
    }
    // ---- leader ranks via ballot prefix ----
    bool islead = (fi == t);
    unsigned long long bal = __ballot(islead);
    int lane = t & 63, wid = t >> 6;
    if ((t & 63) == 0) wtot[wid] = __popcll(bal);
    __syncthreads();
    int woff = 0, U = 0;
    #pragma unroll
    for (int w = 0; w < 8; w++) {
        int c = wtot[w];
        if (w < wid) woff += c;
        U += c;
    }
    if (islead) {
        int r = woff + __popcll(bal & ((1ULL << lane) - 1ULL));
        rk[t] = r;
        ulist[r] = sg[t];
    }
    __syncthreads();
    // ---- accumulate per-unique per-head weights ----
    if (fi >= 0) {
        int h = (t >> 4) & 7;
        atomicAdd(&uw[rk[fi] * 8 + h], sw[t]);
    }
    __syncthreads();
    // ---- main gather: each unique row read once, applied to 2 heads/thread ----
    {
        int ch = t & 255, q = t >> 8;
        float a0 = 0.f, a1 = 0.f;
        for (int u = 0; u < U; u++) {
            int g = ulist[u];
            float v = src[(size_t)g * 256 + ch];
            a0 += uw[u * 8 + 2 * q] * v;
            a1 += uw[u * 8 + 2 * q + 1] * v;
        }
        agg[(2 * q) * 256 + ch] = a0;
        agg[(2 * q + 1) * 256 + ch] = a1;
    }
    // csum partials (deterministic)
    if (t < 64) {
        int h = t >> 3, p = t & 7;
        float s = 0.f;
        for (int u = p; u < U; u += 8) s += uw[u * 8 + h];
        pcs[t] = s;
    }
    __syncthreads();
    // ---- fused value projection: out[h][32] ----
    {
        int h = t >> 7, rem = t & 127, o = rem & 31, kc = rem >> 5;
        const float* ag = agg + h * 256 + kc * 64;
        const float* w = valwT + (size_t)(kc * 64) * 256 + h * 32 + o;
        float pv = 0.f;
        #pragma unroll 8
        for (int i = 0; i < 64; i++) pv += ag[i] * w[(size_t)i * 256];
        pagg[t] = pv;
    }
    __syncthreads();
    if (t < 256) {
        int h = t >> 5, o = t & 31;
        float cs = pcs[h * 8 + 0] + pcs[h * 8 + 1] + pcs[h * 8 + 2] + pcs[h * 8 + 3]
                 + pcs[h * 8 + 4] + pcs[h * 8 + 5] + pcs[h * 8 + 6] + pcs[h * 8 + 7];
        float r = pagg[h * 128 + o] + pagg[h * 128 + 32 + o] + pagg[h * 128 + 64 + o] + pagg[h * 128 + 96 + o];
        ca[(size_t)n * 256 + h * 32 + o] = r + cs * valb[h * 32 + o];
    }
}

// ---------------- S4: pool + oproj + norm1 + ffn1 + ffn2 + norm3 ----------------
// grid 128 (per edge), block 1024; ffn weights bf16-packed
__global__ __launch_bounds__(1024) void k_tail(const float* __restrict__ ca,
                                               const float* __restrict__ x1,
                                               const float* __restrict__ ojwT,
                                               const float* __restrict__ ojb,
                                               const float* __restrict__ n1w,
                                               const float* __restrict__ n1b,
                                               const uint* __restrict__ Pl1,
                                               const float* __restrict__ l1b,
                                               const uint* __restrict__ Pl2,
                                               const float* __restrict__ l2b,
                                               const float* __restrict__ n3w,
                                               const float* __restrict__ n3b,
                                               float* __restrict__ out) {
    int e = blockIdx.x, t = threadIdx.x;
    __shared__ float row[256], red[8], x2s[256], h1s[1024], part[1024];
    if (t < 256)
        row[t] = (ca[(3 * e) * 256 + t] + ca[(3 * e + 1) * 256 + t] + ca[(3 * e + 2) * 256 + t]) * (1.f / 3.f);
    __syncthreads();
    // oproj: 256 outputs x 4 chunks of 64
    {
        int o = t & 255, c = t >> 8;
        float acc = 0.f;
        #pragma unroll 8
        for (int i = c * 64; i < c * 64 + 64; i++) acc += row[i] * ojwT[(size_t)i * 256 + o];
        part[t] = acc;
    }
    __syncthreads();
    // norm1
    {
        float acc = 0.f;
        if (t < 256) acc = part[t] + part[256 + t] + part[512 + t] + part[768 + t] + ojb[t] + x1[e * 256 + t];
        float mean = block_sum256f(acc, red) * (1.f / 256.f);
        float d0 = acc - mean;
        float var = block_sum256f((t < 256) ? d0 * d0 : 0.f, red) * (1.f / 256.f);
        if (t < 256) x2s[t] = d0 * rsqrtf(var + 1e-5f) * n1w[t] + n1b[t];
    }
    __syncthreads();
    // ffn1: one output per thread, packed K=256 (128 uints)
    {
        float acc = l1b[t];
        #pragma unroll 8
        for (int k2 = 0; k2 < 128; k2++) {
            uint u = Pl1[(size_t)k2 * 1024 + t];
            acc += x2s[2 * k2] * lo16(u);
            acc += x2s[2 * k2 + 1] * hi16(u);
        }
        h1s[t] = fmaxf(acc, 0.f);
    }
    __syncthreads();
    // ffn2: 256 outputs x 4 chunks of 128 packed
    {
        int o = t & 255, c = t >> 8;
        float acc = 0.f;
        #pragma unroll 8
        for (int k2 = c * 128; k2 < c * 128 + 128; k2++) {
            uint u = Pl2[(size_t)k2 * 256 + o];
            acc += h1s[2 * k2] * lo16(u);
            acc += h1s[2 * k2 + 1] * hi16(u);
        }
        part[t] = acc;
    }
    __syncthreads();
    // norm3 -> out
    {
        float acc = 0.f;
        if (t < 256) acc = part[t] + part[256 + t] + part[512 + t] + part[768 + t] + l2b[t] + x2s[t];
        float mean = block_sum256f(acc, red) * (1.f / 256.f);
        float d0 = acc - mean;
        float var = block_sum256f((t < 256) ? d0 * d0 : 0.f, red) * (1.f / 256.f);
        if (t < 256) out[e * 256 + t] = d0 * rsqrtf(var + 1e-5f) * n3w[t] + n3b[t];
    }
}

extern "C" void kernel_launch(void* const* d_in, const int* in_sizes, int n_in,
                              void* d_out, int out_size, void* d_ws, size_t ws_size,
                              hipStream_t stream) {
    (void)in_sizes; (void)n_in; (void)out_size; (void)ws_size;
    const float* tgt  = (const float*)d_in[0];
    const float* qpos = (const float*)d_in[1];
    const float* ec   = (const float*)d_in[2];
    const float* src  = (const float*)d_in[3];
    const unsigned char* mask = (const unsigned char*)d_in[4];
    const float* vr   = (const float*)d_in[5];
    const float* ipw  = (const float*)d_in[6];
    const float* ipb  = (const float*)d_in[7];
    const float* opw  = (const float*)d_in[8];
    const float* opb  = (const float*)d_in[9];
    const float* n1w  = (const float*)d_in[10];
    const float* n1b  = (const float*)d_in[11];
    const float* n2w  = (const float*)d_in[12];
    const float* n2b  = (const float*)d_in[13];
    const float* n3w  = (const float*)d_in[14];
    const float* n3b  = (const float*)d_in[15];
    const float* l0w  = (const float*)d_in[16];
    const float* l0b  = (const float*)d_in[17];
    const float* l1w  = (const float*)d_in[18];
    const float* l1b  = (const float*)d_in[19];
    const float* l2w  = (const float*)d_in[20];
    const float* l2b  = (const float*)d_in[21];
    const float* offw = (const float*)d_in[22];
    const float* offb = (const float*)d_in[23];
    const float* aww  = (const float*)d_in[24];
    const float* awb  = (const float*)d_in[25];
    const float* valw = (const float*)d_in[26];
    const float* valb = (const float*)d_in[27];
    const float* ojw  = (const float*)d_in[28];
    const float* ojb  = (const float*)d_in[29];

    float* ws     = (float*)d_ws;
    float* qkv    = ws;                   // 98304
    float* x1     = ws + 98304;           // 32768
    float* offatr = ws + 131072;          // 147456
    float* ca     = ws + 278528;          // 98304
    float* refxy  = ws + 376832;          // 768
    int*   lxly   = (int*)(ws + 377600);  // 3072
    float* opwT   = ws + 380672;          // 65536
    float* ojwT   = ws + 446208;          // 65536
    float* valwT  = ws + 511744;          // 65536
    uint*  Pl1    = (uint*)(ws + 577280); // 131072
    uint*  Pl2    = (uint*)(ws + 708352); // 131072
    uint*  Pl0    = (uint*)(ws + 839424); // 81920
    uint*  Poaw   = (uint*)(ws + 921344); // 49152

    k_prep<<<1152, 256, 0, stream>>>(tgt, qpos, ipw, ipb, opw, ojw, valw, l1w, l2w,
                                     l0w, offw, aww,
                                     qkv, opwT, ojwT, valwT, Pl1, Pl2, Pl0, Poaw);
    k_edge<<<384, 1024, 0, stream>>>(qkv, tgt, qpos, opwT, opb, n2w, n2b, ec,
                                     Pl0, l0b, Poaw, offb, awb,
                                     x1, offatr, refxy, lxly);
    k_sample<<<384, 1024, 0, stream>>>(offatr, refxy, vr, lxly, src, mask, valwT, valb, ca);
    k_tail<<<128, 1024, 0, stream>>>(ca, x1, ojwT, ojb, n1w, n1b, Pl1, l1b, Pl2, l2b, n3w, n3b, (float*)d_out);
}